// Round 8
// baseline (3089.902 us; speedup 1.0000x reference)
//
#include <hip/hip_runtime.h>
#include <math.h>

// ---------------------------------------------------------------------------
// AttentionalSpikingSSMLayer  (B=8, T=16, S=256, D=512, DS=64, H=4, dh=16)
// All compute fp32 (no fp32 MFMA on CDNA4; Heaviside spikes need fp32 margin).
// R1: LIF-O ballot-gather -> dense LDS GEMM (1714 -> 1258 us).
// R2: kv_gemm vectorized LDS; combine gathers -> dense b128 dots (1258->1002).
// R3: NSPLIT 16 + kv conflict fix (neutral) (->1051).
// R4: attp 2q x 128keys, 256 blocks — regressed (->1203).
// R5/R6: persistent kernel — GPU hang: no VGPR cap -> >256 VGPR -> 1 blk/CU
//        -> only 256 of 512 blocks resident -> barrier deadlock.
// R7: __launch_bounds__(256, 2) forces <=256 VGPR (2 waves/SIMD) -> 2 blk/CU
//     capacity = grid (512) -> all blocks resident, barrier safe. LDS
//     62.5KB/block x 2 = 125KB <= 160KB. Single change vs R6.
// ---------------------------------------------------------------------------

#define NTOK   2048          // B*S
#define TSTEPS 16
#define NSPLIT 32            // key splits for flash partials (64 keys each)
#define NBLK   512

#define MEMDECAY ((float)0.6065306597126334)
#define SCALE    0.25f       // 1/sqrt(dh)

// workspace layout (float offsets)
#define OFF_KV   ((size_t)0)                      // 16*2048*128 = 4,194,304
#define OFF_PACC ((size_t)4194304)                // 4*32*2048*16 = 4,194,304
#define OFF_Q    ((size_t)8388608)                // 2048*64 = 131,072
#define OFF_PM   ((size_t)8519680)                // 4*32*2048 = 262,144
#define OFF_PL   ((size_t)8781824)                // 262,144
#define OFF_CT   ((size_t)9043968)                // 64*512 (C transposed)
#define OFF_WT   ((size_t)9076736)                // 512*128 (Wkv transposed)
#define OFF_CNT  ((size_t)9142272)                // 64 ints: [0..15]=s, [16..31]=o, [32]=barrier

// ---------------------------------------------------------------------------
// init: q <- bq (h0=0 => q0=bq), C_t transpose, Wkv_t transpose, zero counters
// and barrier.
// ---------------------------------------------------------------------------
__global__ __launch_bounds__(256) void init_kernel(const float* __restrict__ bq,
                                                   const float* __restrict__ C,
                                                   const float* __restrict__ Wkv,
                                                   float* __restrict__ ws) {
  int i = blockIdx.x * 256 + threadIdx.x;
  if (i < 131072) { ws[OFF_Q + i] = bq[i & 63]; return; }
  i -= 131072;
  if (i < 32768) {                        // C_t[k][c] = C[c][k]
    int k = i >> 9, c = i & 511;
    ws[OFF_CT + i] = C[c * 64 + k];
    return;
  }
  i -= 32768;
  if (i < 65536) {                        // Wkv_t[k][o] = Wkv[o][k]
    int k = i >> 7, o = i & 127;
    ws[OFF_WT + i] = Wkv[o * 512 + k];
    return;
  }
  i -= 65536;
  if (i < 64) ((int*)(ws + OFF_CNT))[i] = 0;
}

// ---------------------------------------------------------------------------
// KV projection for ALL steps (unchanged: conflict-free, LDS-BW bound, ~69us)
// ---------------------------------------------------------------------------
__global__ __launch_bounds__(256) void kv_gemm_kernel(const float* __restrict__ x,
                                                      const float* __restrict__ wkt,
                                                      const float* __restrict__ bkv,
                                                      float* __restrict__ ws) {
  __shared__ float xs[64 * 68];
  __shared__ float wt[64 * 136];
  const int tid = threadIdx.x;
  const int mbase = blockIdx.x * 64;
  const int rg = tid >> 4;
  const int cg = tid & 15;

  float acc[4][8];
#pragma unroll
  for (int i = 0; i < 4; ++i)
#pragma unroll
    for (int j = 0; j < 8; ++j) acc[i][j] = 0.f;

  for (int kt = 0; kt < 8; ++kt) {
    const int kb = kt * 64;
#pragma unroll
    for (int p = 0; p < 4; ++p) {
      int e = tid + p * 256;
      int r = e >> 4, kq = e & 15;
      int row = mbase + r;
      int t_ = row >> 11, n = row & 2047;
      int b = n >> 8, s = n & 255;
      float4 v = *(const float4*)(x + (size_t)((b * 16 + t_) * 256 + s) * 512 + kb + kq * 4);
      *(float4*)(xs + r * 68 + kq * 4) = v;
    }
#pragma unroll
    for (int p = 0; p < 8; ++p) {
      int e = tid + p * 256;
      int k = e >> 5, cq = e & 31;
      float4 v = *(const float4*)(wkt + (size_t)(kb + k) * 128 + cq * 4);
      *(float4*)(wt + k * 136 + cq * 4) = v;
    }
    __syncthreads();
#pragma unroll 2
    for (int kq = 0; kq < 16; ++kq) {
      float4 a0 = *(const float4*)(xs + (rg * 4 + 0) * 68 + kq * 4);
      float4 a1 = *(const float4*)(xs + (rg * 4 + 1) * 68 + kq * 4);
      float4 a2 = *(const float4*)(xs + (rg * 4 + 2) * 68 + kq * 4);
      float4 a3 = *(const float4*)(xs + (rg * 4 + 3) * 68 + kq * 4);
      const float* ap[4] = {(const float*)&a0, (const float*)&a1,
                            (const float*)&a2, (const float*)&a3};
#pragma unroll
      for (int kk = 0; kk < 4; ++kk) {
        const float* wp = wt + (kq * 4 + kk) * 136;
        float4 b0 = *(const float4*)(wp + cg * 4);
        float4 b1 = *(const float4*)(wp + 64 + cg * 4);
#pragma unroll
        for (int i = 0; i < 4; ++i) {
          float av = ap[i][kk];
          acc[i][0] += av * b0.x; acc[i][1] += av * b0.y;
          acc[i][2] += av * b0.z; acc[i][3] += av * b0.w;
          acc[i][4] += av * b1.x; acc[i][5] += av * b1.y;
          acc[i][6] += av * b1.z; acc[i][7] += av * b1.w;
        }
      }
    }
    __syncthreads();
  }
  float4 bb0 = *(const float4*)(bkv + cg * 4);
  float4 bb1 = *(const float4*)(bkv + 64 + cg * 4);
  float* kvout = ws + OFF_KV;
#pragma unroll
  for (int i = 0; i < 4; ++i) {
    float* op = kvout + (size_t)(mbase + rg * 4 + i) * 128;
    float4 v0; v0.x = acc[i][0] + bb0.x; v0.y = acc[i][1] + bb0.y;
    v0.z = acc[i][2] + bb0.z; v0.w = acc[i][3] + bb0.w;
    float4 v1; v1.x = acc[i][4] + bb1.x; v1.y = acc[i][5] + bb1.y;
    v1.z = acc[i][6] + bb1.z; v1.w = acc[i][7] + bb1.w;
    *(float4*)(op + cg * 4) = v0;
    *(float4*)(op + 64 + cg * 4) = v1;
  }
}

// ---------------------------------------------------------------------------
// attention partials (R2 geometry): blk: head(2b) | qtile(2b) | split(5b)
// 256 thr, 2 queries/thread, 64 keys/block.
// ---------------------------------------------------------------------------
__device__ __forceinline__ void attp_body(int blk, int tid, int t,
                                          const float* __restrict__ kvbase,
                                          const float* __restrict__ qbuf,
                                          float* __restrict__ pm,
                                          float* __restrict__ pl,
                                          float* __restrict__ pacc,
                                          float* kl, float* vl) {
  const int head = blk & 3;
  const int qt = (blk >> 2) & 3;
  const int sp = blk >> 4;                 // 0..31
  const float* kvt = kvbase + (size_t)t * NTOK * 128;
  {
    int key = tid >> 2, dq = tid & 3;
    const float* base = kvt + (size_t)(sp * 64 + key) * 128 + head * 16;
    ((float4*)kl)[key * 4 + dq] = ((const float4*)base)[dq];
    ((float4*)vl)[key * 4 + dq] = ((const float4*)(base + 64))[dq];
  }
  const int i0 = qt * 512 + tid;
  const int i1 = i0 + 256;
  float q0[16], q1[16];
  {
    const float4* qp0 = (const float4*)(qbuf + (size_t)i0 * 64 + head * 16);
    const float4* qp1 = (const float4*)(qbuf + (size_t)i1 * 64 + head * 16);
#pragma unroll
    for (int r = 0; r < 4; ++r) {
      float4 a = qp0[r];
      q0[4 * r] = a.x; q0[4 * r + 1] = a.y; q0[4 * r + 2] = a.z; q0[4 * r + 3] = a.w;
      float4 b = qp1[r];
      q1[4 * r] = b.x; q1[4 * r + 1] = b.y; q1[4 * r + 2] = b.z; q1[4 * r + 3] = b.w;
    }
  }
  __syncthreads();
  float m0 = -INFINITY, l0 = 0.f, m1 = -INFINITY, l1 = 0.f;
  float acc0[16], acc1[16];
#pragma unroll
  for (int d = 0; d < 16; ++d) { acc0[d] = 0.f; acc1[d] = 0.f; }

#pragma unroll
  for (int ch = 0; ch < 4; ++ch) {         // 16-key chunks over 64 keys
    float sc0[16], sc1[16];
#pragma unroll
    for (int j = 0; j < 16; ++j) {
      const float* kp = kl + (ch * 16 + j) * 16;
      float s0 = 0.f, s1 = 0.f;
#pragma unroll
      for (int d = 0; d < 16; ++d) { float kv_ = kp[d]; s0 += q0[d] * kv_; s1 += q1[d] * kv_; }
      sc0[j] = s0 * SCALE; sc1[j] = s1 * SCALE;
    }
    float mb0 = sc0[0], mb1 = sc1[0];
#pragma unroll
    for (int j = 1; j < 16; ++j) { mb0 = fmaxf(mb0, sc0[j]); mb1 = fmaxf(mb1, sc1[j]); }
    float mn0 = fmaxf(m0, mb0), mn1 = fmaxf(m1, mb1);
    float r0 = expf(m0 - mn0), r1 = expf(m1 - mn1);
    l0 *= r0; l1 *= r1;
#pragma unroll
    for (int d = 0; d < 16; ++d) { acc0[d] *= r0; acc1[d] *= r1; }
#pragma unroll
    for (int j = 0; j < 16; ++j) {
      float w0 = expf(sc0[j] - mn0), w1 = expf(sc1[j] - mn1);
      l0 += w0; l1 += w1; sc0[j] = w0; sc1[j] = w1;
    }
#pragma unroll
    for (int j = 0; j < 16; ++j) {
      const float* vp = vl + (ch * 16 + j) * 16;
      float w0 = sc0[j], w1 = sc1[j];
#pragma unroll
      for (int d = 0; d < 16; ++d) { float vv = vp[d]; acc0[d] += w0 * vv; acc1[d] += w1 * vv; }
    }
    m0 = mn0; m1 = mn1;
  }
  const int pbase = (head * NSPLIT + sp) * NTOK;
  pm[pbase + i0] = m0; pm[pbase + i1] = m1;
  pl[pbase + i0] = l0; pl[pbase + i1] = l1;
  float4* pa0 = (float4*)(pacc + (size_t)(pbase + i0) * 16);
  float4* pa1 = (float4*)(pacc + (size_t)(pbase + i1) * 16);
#pragma unroll
  for (int r = 0; r < 4; ++r) {
    float4 v0; v0.x = acc0[4 * r]; v0.y = acc0[4 * r + 1];
    v0.z = acc0[4 * r + 2]; v0.w = acc0[4 * r + 3];
    pa0[r] = v0;
    float4 v1; v1.x = acc1[4 * r]; v1.y = acc1[4 * r + 1];
    v1.z = acc1[4 * r + 2]; v1.w = acc1[4 * r + 3];
    pa1[r] = v1;
  }
}

// ---------------------------------------------------------------------------
// hand-rolled grid barrier (agent scope). All 512 blocks co-resident:
// launch_bounds(256,2) caps VGPR<=256 (2 waves/SIMD) and LDS 62.5KB*2<=160KB.
// ---------------------------------------------------------------------------
__device__ __forceinline__ void gbar(int* bar, int target, int tid) {
  __syncthreads();
  if (tid == 0) {
    __hip_atomic_fetch_add(bar, 1, __ATOMIC_ACQ_REL, __HIP_MEMORY_SCOPE_AGENT);
    while (__hip_atomic_load(bar, __ATOMIC_ACQUIRE, __HIP_MEMORY_SCOPE_AGENT) < target)
      __builtin_amdgcn_s_sleep(2);
  }
  __syncthreads();
}

// ---------------------------------------------------------------------------
// persistent kernel. Grid 512 x 256. Per block: 4 tokens owned forever.
// Loop: [bar] combine(t) -> q,spikes  [bar] attp(t+1) + out(t).
// ---------------------------------------------------------------------------
__global__ __launch_bounds__(256, 2) void persistent_kernel(
    const float* __restrict__ A, const float* __restrict__ Wq,
    const float* __restrict__ bq, const float* __restrict__ Wo,
    const float* __restrict__ bo, const float* __restrict__ th_s,
    const float* __restrict__ th_o, float* __restrict__ out,
    float* __restrict__ ws) {
  __shared__ float As[64 * 68], Wqs[64 * 68], Wos[64 * 68];  // 52.2 KB
  __shared__ float kl[1024], vl[1024];                       // 8 KB (attp)
  __shared__ float att_s[256], sp_s[256];                    // 2 KB
  __shared__ int scnt, scnt_o, cnt_l[16];

  const int tid = threadIdx.x;
  const int blk = blockIdx.x;
  const int lane = tid & 63, w = tid >> 6;

  float* pm = ws + OFF_PM;
  float* pl = ws + OFF_PL;
  float* pacc = ws + OFF_PACC;
  float* qb = ws + OFF_Q;
  int* cnt = (int*)(ws + OFF_CNT);
  int* bar = cnt + 32;

  // stage weights once (row-major, stride 68 => 16B-aligned rows)
#pragma unroll
  for (int p = 0; p < 4; ++p) {
    int e = tid + p * 256;
    int c = e >> 4, kq = e & 15;
    *(float4*)(As + c * 68 + kq * 4)  = *(const float4*)(A + c * 64 + kq * 4);
    *(float4*)(Wqs + c * 68 + kq * 4) = *(const float4*)(Wq + c * 64 + kq * 4);
    *(float4*)(Wos + c * 68 + kq * 4) = *(const float4*)(Wo + c * 64 + kq * 4);
  }
  sp_s[tid] = 0.f;                 // h(-1) = 0
  float sv_reg = 0.f;              // sv for own token (wave w -> token blk*4+w)
  float ov0x = 0.f, ov0y = 0.f, ov1x = 0.f, ov1y = 0.f;
  float ov2x = 0.f, ov2y = 0.f, ov3x = 0.f, ov3y = 0.f;   // ov[4 tok][2 ch]

  attp_body(blk, tid, 0, ws + OFF_KV, qb, pm, pl, pacc, kl, vl);

  const int n = blk * 4 + w;
  const int head = lane >> 4, d = lane & 15;
  const int pb = head * NSPLIT * NTOK + n;
  const float thr_s_init = th_s[0];
  const float thr_o_init = th_o[0];
  const float bo_l = bo[lane];
  const float bq_l = bq[lane];
  const int c0 = w * 128 + lane * 2;       // out channels {c0, c0+1}
  const float* Ct = ws + OFF_CT;

  int bcount = 0;
  for (int t = 0; t < TSTEPS; ++t) {
    gbar(bar, NBLK * (++bcount), tid);
    // ---- phase A: combine + LIF-S + q(t+1) ----
    if (tid == 0) { scnt = 0; scnt_o = 0; }
    if (tid < 16)   // agent-scope load: safe vs per-XCD L2 non-coherence
      cnt_l[tid] = __hip_atomic_load(&cnt[tid], __ATOMIC_RELAXED,
                                     __HIP_MEMORY_SCOPE_AGENT);
    float mstar = -INFINITY;
#pragma unroll
    for (int s = 0; s < NSPLIT; ++s) mstar = fmaxf(mstar, pm[pb + s * NTOK]);
    float lst = 0.f, av = 0.f;
#pragma unroll
    for (int s = 0; s < NSPLIT; ++s) {
      float e = expf(pm[pb + s * NTOK] - mstar);
      lst += e * pl[pb + s * NTOK];
      av += e * pacc[(size_t)(pb + s * NTOK) * 16 + d];
    }
    att_s[w * 64 + lane] = av / lst;

    const float* Ar = As + lane * 68;
    const float* Wor = Wos + lane * 68;
    float st = 0.f, wo = 0.f;
#pragma unroll
    for (int kq = 0; kq < 16; ++kq) {
      float4 wa = *(const float4*)(Ar + kq * 4);
      float4 wb = *(const float4*)(Wor + kq * 4);
      float4 hb = *(const float4*)(&sp_s[w * 64 + kq * 4]);   // OLD spikes
      float4 ab = *(const float4*)(&att_s[w * 64 + kq * 4]);  // same-wave LDS
      st += hb.x * wa.x; st += hb.y * wa.y; st += hb.z * wa.z; st += hb.w * wa.w;
      wo += ab.x * wb.x; wo += ab.y * wb.y; wo += ab.z * wb.z; wo += ab.w * wb.w;
    }
    float su = st + wo + bo_l;
    __syncthreads();                       // cnt_l visibility (wave0 wrote it)

    float thr = thr_s_init;
    const float inv_s = 1.0f / 131072.0f;  // 2048*64 (power of 2 -> exact)
    for (int i = 0; i < t; ++i) {
      float mean = (float)cnt_l[i] * inv_s;
      thr = fmaxf(thr + 0.1f * (mean - 0.02f), 0.5f);
    }
    float vpot = sv_reg * MEMDECAY + su;
    float spk = (vpot >= thr) ? 1.f : 0.f;
    sv_reg = vpot * (1.f - spk);
    sp_s[w * 64 + lane] = spk;             // NEW spikes (own-wave write)
    unsigned long long sm = __ballot(spk > 0.5f);

    const float* Wqr = Wqs + lane * 68;
    float qv = 0.f;
#pragma unroll
    for (int kq = 0; kq < 16; ++kq) {
      float4 wq = *(const float4*)(Wqr + kq * 4);
      float4 sb = *(const float4*)(&sp_s[w * 64 + kq * 4]);   // NEW (same wave)
      qv += sb.x * wq.x; qv += sb.y * wq.y; qv += sb.z * wq.z; qv += sb.w * wq.w;
    }
    qb[n * 64 + lane] = qv + bq_l;
    if (lane == 0) atomicAdd(&scnt, __popcll(sm));
    __syncthreads();
    if (tid == 0)
      __hip_atomic_fetch_add(&cnt[t], scnt, __ATOMIC_RELAXED,
                             __HIP_MEMORY_SCOPE_AGENT);

    gbar(bar, NBLK * (++bcount), tid);
    // ---- phase B: attp(t+1) + out(t) ----
    if (t < TSTEPS - 1)
      attp_body(blk, tid, t + 1, ws + OFF_KV, qb, pm, pl, pacc, kl, vl);

    if (tid < 16)
      cnt_l[tid] = __hip_atomic_load(&cnt[16 + tid], __ATOMIC_RELAXED,
                                     __HIP_MEMORY_SCOPE_AGENT);
    __syncthreads();                       // cnt_l + cross-wave sp_s ready

    float thro = thr_o_init;
    const float inv_o = 1.0f / 1048576.0f; // 2048*512
    for (int i = 0; i < t; ++i) {
      float mean = (float)cnt_l[i] * inv_o;
      thro = fmaxf(thro + 0.1f * (mean - 0.02f), 0.5f);
    }
    // out_pot[tok][c] = sum_k spk[tok][k] * C_t[k][c], k ascending
    float a0x = 0.f, a0y = 0.f, a1x = 0.f, a1y = 0.f;
    float a2x = 0.f, a2y = 0.f, a3x = 0.f, a3y = 0.f;
#pragma unroll 4
    for (int kq = 0; kq < 16; ++kq) {
      float4 h0 = *(const float4*)(&sp_s[kq * 4]);
      float4 h1 = *(const float4*)(&sp_s[64 + kq * 4]);
      float4 h2 = *(const float4*)(&sp_s[128 + kq * 4]);
      float4 h3 = *(const float4*)(&sp_s[192 + kq * 4]);
      const float* hp0 = (const float*)&h0;
      const float* hp1 = (const float*)&h1;
      const float* hp2 = (const float*)&h2;
      const float* hp3 = (const float*)&h3;
#pragma unroll
      for (int j = 0; j < 4; ++j) {
        float2 cv = *(const float2*)(Ct + (size_t)(kq * 4 + j) * 512 + c0);
        a0x += hp0[j] * cv.x; a0y += hp0[j] * cv.y;
        a1x += hp1[j] * cv.x; a1y += hp1[j] * cv.y;
        a2x += hp2[j] * cv.x; a2y += hp2[j] * cv.y;
        a3x += hp3[j] * cv.x; a3y += hp3[j] * cv.y;
      }
    }
    int mycnt = 0;
    {
      float v0 = ov0x * MEMDECAY + a0x, v1 = ov0y * MEMDECAY + a0y;
      float s0 = (v0 >= thro) ? 1.f : 0.f, s1 = (v1 >= thro) ? 1.f : 0.f;
      ov0x = v0 * (1.f - s0); ov0y = v1 * (1.f - s1);
      int n0 = blk * 4 + 0; int b = n0 >> 8, s = n0 & 255;
      float2 sp; sp.x = s0; sp.y = s1;
      *(float2*)(out + ((size_t)(b * 16 + t) * 256 + s) * 512 + c0) = sp;
      mycnt += __popcll(__ballot(s0 > 0.5f)) + __popcll(__ballot(s1 > 0.5f));
    }
    {
      float v0 = ov1x * MEMDECAY + a1x, v1 = ov1y * MEMDECAY + a1y;
      float s0 = (v0 >= thro) ? 1.f : 0.f, s1 = (v1 >= thro) ? 1.f : 0.f;
      ov1x = v0 * (1.f - s0); ov1y = v1 * (1.f - s1);
      int n0 = blk * 4 + 1; int b = n0 >> 8, s = n0 & 255;
      float2 sp; sp.x = s0; sp.y = s1;
      *(float2*)(out + ((size_t)(b * 16 + t) * 256 + s) * 512 + c0) = sp;
      mycnt += __popcll(__ballot(s0 > 0.5f)) + __popcll(__ballot(s1 > 0.5f));
    }
    {
      float v0 = ov2x * MEMDECAY + a2x, v1 = ov2y * MEMDECAY + a2y;
      float s0 = (v0 >= thro) ? 1.f : 0.f, s1 = (v1 >= thro) ? 1.f : 0.f;
      ov2x = v0 * (1.f - s0); ov2y = v1 * (1.f - s1);
      int n0 = blk * 4 + 2; int b = n0 >> 8, s = n0 & 255;
      float2 sp; sp.x = s0; sp.y = s1;
      *(float2*)(out + ((size_t)(b * 16 + t) * 256 + s) * 512 + c0) = sp;
      mycnt += __popcll(__ballot(s0 > 0.5f)) + __popcll(__ballot(s1 > 0.5f));
    }
    {
      float v0 = ov3x * MEMDECAY + a3x, v1 = ov3y * MEMDECAY + a3y;
      float s0 = (v0 >= thro) ? 1.f : 0.f, s1 = (v1 >= thro) ? 1.f : 0.f;
      ov3x = v0 * (1.f - s0); ov3y = v1 * (1.f - s1);
      int n0 = blk * 4 + 3; int b = n0 >> 8, s = n0 & 255;
      float2 sp; sp.x = s0; sp.y = s1;
      *(float2*)(out + ((size_t)(b * 16 + t) * 256 + s) * 512 + c0) = sp;
      mycnt += __popcll(__ballot(s0 > 0.5f)) + __popcll(__ballot(s1 > 0.5f));
    }
    if (lane == 0) atomicAdd(&scnt_o, mycnt);
    __syncthreads();
    if (tid == 0)
      __hip_atomic_fetch_add(&cnt[16 + t], scnt_o, __ATOMIC_RELAXED,
                             __HIP_MEMORY_SCOPE_AGENT);
  }
}

// ---------------------------------------------------------------------------
extern "C" void kernel_launch(void* const* d_in, const int* in_sizes, int n_in,
                              void* d_out, int out_size, void* d_ws, size_t ws_size,
                              hipStream_t stream) {
  const float* x    = (const float*)d_in[0];
  const float* A    = (const float*)d_in[1];
  const float* C    = (const float*)d_in[2];
  const float* Wq   = (const float*)d_in[3];
  const float* bq   = (const float*)d_in[4];
  const float* Wkv  = (const float*)d_in[5];
  const float* bkv  = (const float*)d_in[6];
  const float* Wo   = (const float*)d_in[7];
  const float* bo   = (const float*)d_in[8];
  const float* th_s = (const float*)d_in[9];
  const float* th_o = (const float*)d_in[10];
  float* out = (float*)d_out;
  float* ws = (float*)d_ws;

  init_kernel<<<dim3(897), dim3(256), 0, stream>>>(bq, C, Wkv, ws);
  kv_gemm_kernel<<<dim3(512), dim3(256), 0, stream>>>(x, ws + OFF_WT, bkv, ws);
  persistent_kernel<<<dim3(NBLK), dim3(256), 0, stream>>>(
      A, Wq, bq, Wo, bo, th_s, th_o, out, ws);
}